// Round 16
// baseline (4681.377 us; speedup 1.0000x reference)
//
#include <hip/hip_runtime.h>
#include <hip/hip_bf16.h>

// ---------------- helpers ----------------
__device__ inline float fsig(float x) { return 1.0f / (1.0f + __expf(-x)); }
__device__ inline float ftanh(float x) {
    float ax = fabsf(x);
    float e = __expf(-2.0f * ax);
    float r = (1.0f - e) / (1.0f + e);
    return x >= 0.0f ? r : -r;
}
__device__ inline float felu(float x) { return x > 0.0f ? x : expm1f(x); }

typedef _Float16 h2_t __attribute__((ext_vector_type(2)));
typedef _Float16 f16x8 __attribute__((ext_vector_type(8)));
typedef float f32x4 __attribute__((ext_vector_type(4)));

__device__ inline unsigned int packh2(float a, float b) {
    unsigned short ua = __builtin_bit_cast(unsigned short, (_Float16)a);
    unsigned short ub = __builtin_bit_cast(unsigned short, (_Float16)b);
    return (unsigned int)ua | ((unsigned int)ub << 16);
}
__device__ inline unsigned short f16bits(float a) {
    return __builtin_bit_cast(unsigned short, (_Float16)a);
}

__device__ inline float dot2acc(unsigned int w, unsigned int h, float acc) {
#if __has_builtin(__builtin_amdgcn_fdot2)
    return __builtin_amdgcn_fdot2(__builtin_bit_cast(h2_t, w), __builtin_bit_cast(h2_t, h), acc, false);
#else
    _Float16 wlo = __builtin_bit_cast(_Float16, (unsigned short)(w & 0xffff));
    _Float16 whi = __builtin_bit_cast(_Float16, (unsigned short)(w >> 16));
    _Float16 hlo = __builtin_bit_cast(_Float16, (unsigned short)(h & 0xffff));
    _Float16 hhi = __builtin_bit_cast(_Float16, (unsigned short)(h >> 16));
    return acc + (float)wlo * (float)hlo + (float)whi * (float)hhi;
#endif
}

// ---------------- convert lstm_w rows [0,1152) to f16 TRANSPOSED [n][k], LDS-tiled ----
__global__ __launch_bounds__(256) void convert_lwT(const float* __restrict__ lw,
                                                   unsigned short* __restrict__ lwhT) {
    __shared__ float tile[32][33];
    const int kb = blockIdx.x * 32;
    const int nb = blockIdx.y * 32;
    const int tx = threadIdx.x & 31, ty = threadIdx.x >> 5;
    for (int i = ty; i < 32; i += 8)
        tile[i][tx] = lw[(size_t)(kb + i) * 1024 + nb + tx];     // coalesced along n
    __syncthreads();
    for (int i = ty; i < 32; i += 8)
        lwhT[(size_t)(nb + i) * 1152 + kb + tx] = f16bits(tile[tx][i]);  // coalesced along k
}

// ---------------- conv0: f32 in (CIN=4), f16 out ----------------
__global__ __launch_bounds__(256) void conv0_kernel(const float* __restrict__ in,
                                                    const float* __restrict__ wg,
                                                    const float* __restrict__ bias,
                                                    unsigned short* __restrict__ out) {
    constexpr int W = 84, OW = 42, PAD = 0, WP = W + 2;
    __shared__ float in_s[3 * WP * 4];
    constexpr int NQ = 3 * WP;
    const int tid = threadIdx.x;
    const int oy = blockIdx.x;
    const int t = blockIdx.y;
    const int co = tid & 31;

    for (int q = tid; q < NQ; q += 256) {
        int ky = q / WP;
        int col = q - ky * WP;
        int iy = 2 * oy - PAD + ky;
        int ix = col - 1;
        float4 v = make_float4(0.f, 0.f, 0.f, 0.f);
        if (iy >= 0 && iy < W && ix >= 0 && ix < W)
            v = *(const float4*)&in[(((size_t)t * W + iy) * W + ix) * 4];
        *(float4*)&in_s[q * 4] = v;
    }

    float wr[9][4];
#pragma unroll
    for (int tap = 0; tap < 9; ++tap)
#pragma unroll
        for (int j = 0; j < 4; ++j) wr[tap][j] = wg[(tap * 4 + j) * 32 + co];
    __syncthreads();

    const int g = tid >> 5;
    constexpr int NOX = (OW + 7) / 8;
    float acc[NOX];
#pragma unroll
    for (int m = 0; m < NOX; ++m) acc[m] = 0.f;
#pragma unroll
    for (int ky = 0; ky < 3; ++ky)
#pragma unroll
        for (int kx = 0; kx < 3; ++kx) {
            float w0 = wr[ky * 3 + kx][0], w1 = wr[ky * 3 + kx][1];
            float w2 = wr[ky * 3 + kx][2], w3 = wr[ky * 3 + kx][3];
#pragma unroll
            for (int m = 0; m < NOX; ++m) {
                int ox = g + 8 * m;
                if (ox < OW) {
                    int cs = 2 * ox + kx - PAD + 1;
                    float4 xi = *(const float4*)&in_s[(ky * WP + cs) * 4];
                    acc[m] += xi.x * w0 + xi.y * w1 + xi.z * w2 + xi.w * w3;
                }
            }
        }
    float b = bias[co];
#pragma unroll
    for (int m = 0; m < NOX; ++m) {
        int ox = g + 8 * m;
        if (ox < OW)
            out[(((size_t)t * OW + oy) * OW + ox) * 32 + co] = f16bits(felu(acc[m] + b));
    }
}

// ---------------- convh: f16 in (CIN=32), 2 co per thread ----------------
template <int W, int OW, int PAD, bool F32OUT>
__global__ __launch_bounds__(256) void convh_kernel(const unsigned short* __restrict__ in,
                                                    const float* __restrict__ wg,
                                                    const float* __restrict__ bias,
                                                    void* __restrict__ outv) {
    constexpr int WP = W + 2;
    constexpr int OWQ = (OW + 3) / 4;
    __shared__ __align__(16) unsigned short in_s[3][WP][32];
    __shared__ float zs[4][OW * 32];

    const int tid = threadIdx.x;
    const int oy = blockIdx.x;
    const int t = blockIdx.y;
    const int co16 = tid & 15;
    const int cig = (tid >> 4) & 3;
    const int oxq = tid >> 6;

    constexpr int NQ4 = 3 * WP * 4;
    uint4* in_s4 = reinterpret_cast<uint4*>(&in_s[0][0][0]);
    for (int q = tid; q < NQ4; q += 256) {
        int ky = q / (WP * 4);
        int rem = q - ky * (WP * 4);
        int col = rem >> 2, c4 = rem & 3;
        int iy = 2 * oy - PAD + ky;
        int ix = col - 1;
        uint4 v = make_uint4(0u, 0u, 0u, 0u);
        if (iy >= 0 && iy < W && ix >= 0 && ix < W)
            v = *(const uint4*)&in[(((size_t)t * W + iy) * W + ix) * 32 + c4 * 8];
        in_s4[q] = v;
    }

    unsigned int wr[9][4][2];
#pragma unroll
    for (int tap = 0; tap < 9; ++tap)
#pragma unroll
        for (int p = 0; p < 4; ++p) {
            wr[tap][p][0] = packh2(wg[(tap * 32 + cig * 8 + 2 * p) * 32 + co16],
                                   wg[(tap * 32 + cig * 8 + 2 * p + 1) * 32 + co16]);
            wr[tap][p][1] = packh2(wg[(tap * 32 + cig * 8 + 2 * p) * 32 + co16 + 16],
                                   wg[(tap * 32 + cig * 8 + 2 * p + 1) * 32 + co16 + 16]);
        }
    __syncthreads();

    float acc0[OWQ], acc1[OWQ];
#pragma unroll
    for (int m = 0; m < OWQ; ++m) { acc0[m] = 0.f; acc1[m] = 0.f; }
#pragma unroll
    for (int ky = 0; ky < 3; ++ky)
#pragma unroll
        for (int kx = 0; kx < 3; ++kx) {
            const int tap = ky * 3 + kx;
#pragma unroll
            for (int m = 0; m < OWQ; ++m) {
                int ox = oxq * OWQ + m;
                if (ox < OW) {
                    int cs = 2 * ox + kx - PAD + 1;
                    uint4 h8 = *(const uint4*)&in_s[ky][cs][cig * 8];
                    acc0[m] = dot2acc(wr[tap][0][0], h8.x, acc0[m]);
                    acc0[m] = dot2acc(wr[tap][1][0], h8.y, acc0[m]);
                    acc0[m] = dot2acc(wr[tap][2][0], h8.z, acc0[m]);
                    acc0[m] = dot2acc(wr[tap][3][0], h8.w, acc0[m]);
                    acc1[m] = dot2acc(wr[tap][0][1], h8.x, acc1[m]);
                    acc1[m] = dot2acc(wr[tap][1][1], h8.y, acc1[m]);
                    acc1[m] = dot2acc(wr[tap][2][1], h8.z, acc1[m]);
                    acc1[m] = dot2acc(wr[tap][3][1], h8.w, acc1[m]);
                }
            }
        }
#pragma unroll
    for (int m = 0; m < OWQ; ++m) {
        int ox = oxq * OWQ + m;
        if (ox < OW) {
            zs[cig][ox * 32 + co16] = acc0[m];
            zs[cig][ox * 32 + co16 + 16] = acc1[m];
        }
    }
    __syncthreads();

    for (int idx = tid; idx < OW * 32; idx += 256) {
        float s = zs[0][idx] + zs[1][idx] + zs[2][idx] + zs[3][idx] + bias[idx & 31];
        s = felu(s);
        if constexpr (F32OUT)
            ((float*)outv)[(((size_t)t * OW + oy) * OW) * 32 + idx] = s;
        else
            ((unsigned short*)outv)[(((size_t)t * OW + oy) * OW) * 32 + idx] = f16bits(s);
    }
}

// ---------------- xpart GEMM via MFMA f16 (round-15, unchanged) ----------------
__global__ __launch_bounds__(256) void gemm_mfma(const unsigned short* __restrict__ A,
                                                 const unsigned short* __restrict__ BT,
                                                 const float* __restrict__ bias,
                                                 float* __restrict__ C) {
    __shared__ __align__(16) unsigned short As[64][40];
    __shared__ __align__(16) unsigned short Bs[64][40];
    const int bn = blockIdx.x;
    const int bm = blockIdx.y;
    const int tid = threadIdx.x;
    const int wv = tid >> 6;
    const int l = tid & 63;
    const int lm = l & 15;
    const int kg = l >> 4;

    f32x4 acc[4] = {};

    const int sr = tid >> 2;
    const int sk = (tid & 3) * 8;

    for (int k0 = 0; k0 < 1152; k0 += 32) {
        *(uint4*)&As[sr][sk] = *(const uint4*)&A[(size_t)(bm * 64 + sr) * 1152 + k0 + sk];
        *(uint4*)&Bs[sr][sk] = *(const uint4*)&BT[(size_t)(bn * 64 + sr) * 1152 + k0 + sk];
        __syncthreads();

        f16x8 a = *(const f16x8*)&As[(wv << 4) + lm][kg * 8];
        f16x8 b0 = *(const f16x8*)&Bs[lm][kg * 8];
        f16x8 b1 = *(const f16x8*)&Bs[16 + lm][kg * 8];
        f16x8 b2 = *(const f16x8*)&Bs[32 + lm][kg * 8];
        f16x8 b3 = *(const f16x8*)&Bs[48 + lm][kg * 8];
        acc[0] = __builtin_amdgcn_mfma_f32_16x16x32_f16(a, b0, acc[0], 0, 0, 0);
        acc[1] = __builtin_amdgcn_mfma_f32_16x16x32_f16(a, b1, acc[1], 0, 0, 0);
        acc[2] = __builtin_amdgcn_mfma_f32_16x16x32_f16(a, b2, acc[2], 0, 0, 0);
        acc[3] = __builtin_amdgcn_mfma_f32_16x16x32_f16(a, b3, acc[3], 0, 0, 0);
        __syncthreads();
    }

#pragma unroll
    for (int nt = 0; nt < 4; ++nt) {
        int col = bn * 64 + nt * 16 + lm;
        float bv = bias[col];
#pragma unroll
        for (int j = 0; j < 4; ++j) {
            int row = bm * 64 + (wv << 4) + kg * 4 + j;
            C[(size_t)row * 1024 + col] = acc[nt][j] + bv;
        }
    }
}

// ---------------- LSTM lstm10: lstm7 + SGPR h-broadcast via readlane ----------------
// Per wave per step: ONE ds_read_b128 loads the wave's 256B h-half into lanes 0..15
// (chunk = lane&15); readlane lifts each uint to an SGPR (uniform), and dot2 (VOP3P,
// 1 scalar source allowed) consumes h from SGPRs. Replaces lstm7's 16 uniform b128
// reads/wave (-1440 cyc/step CU-wide LDS) for +64 readlane/wave VALU. Gates + xp
// prefetch restricted to tid<256 (removes x2-redundant gate VALU + zsm reads).
// Accumulation order identical to lstm7 -> bit-identical output.
__global__ __attribute__((amdgpu_flat_work_group_size(512, 512)))
void lstm10_kernel(const float* __restrict__ lstm_w,
                   const float* __restrict__ xpart,
                   const float* __restrict__ c_in,
                   const float* __restrict__ h_in,
                   float* __restrict__ hs_out) {
    __shared__ __align__(16) unsigned int wl[512][52];
    __shared__ float zsm[2][4][256];
    __shared__ __align__(16) unsigned int hpk[2][2][68];

    const int tid = threadIdx.x;
    const int s = tid >> 8;    // k-half (uniform per wave: waves 0-3 s=0, 4-7 s=1)
    const int u = tid & 255;   // unit / column group

    for (int q = 0; q < 4; ++q)
        for (int p = 0; p < 12; ++p) {
            int gp = 64 * s + p;
            wl[tid][q * 12 + p] = packh2(lstm_w[(size_t)(1152 + 2 * gp) * 1024 + (q << 8) + u],
                                         lstm_w[(size_t)(1152 + 2 * gp + 1) * 1024 + (q << 8) + u]);
        }
    unsigned int wreg[4][52];
#pragma unroll
    for (int q = 0; q < 4; ++q)
        for (int p = 12; p < 64; ++p) {
            int gp = 64 * s + p;
            wreg[q][p - 12] = packh2(lstm_w[(size_t)(1152 + 2 * gp) * 1024 + (q << 8) + u],
                                     lstm_w[(size_t)(1152 + 2 * gp + 1) * 1024 + (q << 8) + u]);
        }

    float c_state = c_in[u];
    if (tid < 256) {
        unsigned short* hrow = (unsigned short*)&hpk[0][u >> 7][0];
        hrow[u & 127] = f16bits(h_in[u]);
    }
    __syncthreads();

    float xp0 = 0.f, xp1 = 0.f, xp2 = 0.f, xp3 = 0.f;
    if (tid < 256) {
        xp0 = xpart[u]; xp1 = xpart[256 + u]; xp2 = xpart[512 + u]; xp3 = xpart[768 + u];
    }

    for (int t = 0; t < 2048; ++t) {
        const int cur = t & 1;
        // one b128/wave: lane l holds 16B chunk (l&15) of this wave's h-half
        uint4 hv = *(const uint4*)&hpk[cur][s][(tid & 15) * 4];

        // stage this step's LDS weights (12 b128/thread, as lstm7)
        unsigned int wlo[4][12];
#pragma unroll
        for (int q = 0; q < 4; ++q) {
            *(uint4*)&wlo[q][0] = *(const uint4*)&wl[tid][q * 12 + 0];
            *(uint4*)&wlo[q][4] = *(const uint4*)&wl[tid][q * 12 + 4];
            *(uint4*)&wlo[q][8] = *(const uint4*)&wl[tid][q * 12 + 8];
        }

        float a0 = 0.f, a1 = 0.f, a2 = 0.f, a3 = 0.f;
#pragma unroll
        for (int c = 0; c < 4; ++c) {
            unsigned int hsg[16];   // uniform (SGPR) h pairs 16c..16c+15
#pragma unroll
            for (int j = 0; j < 16; ++j) {
                const int comp = j & 3;
                unsigned int src = comp == 0 ? hv.x : comp == 1 ? hv.y : comp == 2 ? hv.z : hv.w;
                hsg[j] = __builtin_amdgcn_readlane(src, 4 * c + (j >> 2));
            }
#pragma unroll
            for (int j = 0; j < 16; ++j) {
                const int p = c * 16 + j;
                const unsigned int w0 = (p < 12) ? wlo[0][p < 12 ? p : 0] : wreg[0][p >= 12 ? p - 12 : 0];
                const unsigned int w1 = (p < 12) ? wlo[1][p < 12 ? p : 0] : wreg[1][p >= 12 ? p - 12 : 0];
                const unsigned int w2 = (p < 12) ? wlo[2][p < 12 ? p : 0] : wreg[2][p >= 12 ? p - 12 : 0];
                const unsigned int w3 = (p < 12) ? wlo[3][p < 12 ? p : 0] : wreg[3][p >= 12 ? p - 12 : 0];
                a0 = dot2acc(w0, hsg[j], a0);
                a1 = dot2acc(w1, hsg[j], a1);
                a2 = dot2acc(w2, hsg[j], a2);
                a3 = dot2acc(w3, hsg[j], a3);
            }
        }
        zsm[s][0][u] = a0;
        zsm[s][1][u] = a1;
        zsm[s][2][u] = a2;
        zsm[s][3][u] = a3;

        float xn0 = 0.f, xn1 = 0.f, xn2 = 0.f, xn3 = 0.f;
        if (tid < 256 && t + 1 < 2048) {
            const float* xr = &xpart[(size_t)(t + 1) * 1024];
            xn0 = xr[u]; xn1 = xr[256 + u]; xn2 = xr[512 + u]; xn3 = xr[768 + u];
        }

        asm volatile("s_waitcnt lgkmcnt(0)\n\ts_barrier" ::: "memory");

        if (tid < 256) {
            float zi = zsm[0][0][u] + zsm[1][0][u] + xp0;
            float zj = zsm[0][1][u] + zsm[1][1][u] + xp1;
            float zf = zsm[0][2][u] + zsm[1][2][u] + xp2;
            float zo = zsm[0][3][u] + zsm[1][3][u] + xp3;
            c_state = c_state * fsig(zf + 1.0f) + fsig(zi) * ftanh(zj);
            float h = ftanh(c_state) * fsig(zo);
            hs_out[(size_t)t * 256 + u] = h;
            unsigned short* hrow = (unsigned short*)&hpk[cur ^ 1][u >> 7][0];
            hrow[u & 127] = f16bits(h);
        }

        asm volatile("s_waitcnt lgkmcnt(0)\n\ts_barrier" ::: "memory");
        xp0 = xn0; xp1 = xn1; xp2 = xn2; xp3 = xn3;
    }
}

// ---------------- logits ----------------
__global__ void logits_kernel(const float* __restrict__ hs, const float* __restrict__ fc_w,
                              const float* __restrict__ fc_b, float* __restrict__ out) {
    int idx = blockIdx.x * 256 + threadIdx.x;
    if (idx >= 2048 * 18) return;
    int t = idx / 18, n = idx % 18;
    float acc = fc_b[n];
    const float* hrow = hs + (size_t)t * 256;
#pragma unroll 4
    for (int k = 0; k < 256; ++k) acc += hrow[k] * fc_w[k * 18 + n];
    out[idx] = acc;
}

// ---------------- launch ----------------
extern "C" void kernel_launch(void* const* d_in, const int* in_sizes, int n_in,
                              void* d_out, int out_size, void* d_ws, size_t ws_size,
                              hipStream_t stream) {
    const float* x   = (const float*)d_in[0];
    const float* w0  = (const float*)d_in[1];
    const float* b0  = (const float*)d_in[2];
    const float* w1  = (const float*)d_in[3];
    const float* b1  = (const float*)d_in[4];
    const float* w2  = (const float*)d_in[5];
    const float* b2  = (const float*)d_in[6];
    const float* w3  = (const float*)d_in[7];
    const float* b3  = (const float*)d_in[8];
    const float* lw  = (const float*)d_in[9];
    const float* lb  = (const float*)d_in[10];
    const float* fcw = (const float*)d_in[11];
    const float* fcb = (const float*)d_in[12];
    const float* cin = (const float*)d_in[13];
    const float* hin = (const float*)d_in[14];

    float* outp = (float*)d_out;
    float* hs_out = outp + 2048 * 18;

    float* xpart = (float*)d_ws;
    unsigned short* feats16 = (unsigned short*)(xpart + (size_t)2048 * 1024);
    unsigned short* lwhT = feats16 + (size_t)2048 * 1152;
    unsigned short* bufs = lwhT + (size_t)1024 * 1152;

    const size_t FIXED_B = (size_t)2048 * 1024 * 4 + (size_t)2048 * 1152 * 2 +
                           (size_t)1024 * 1152 * 2;
    const size_t PERT_B = ((size_t)56448 + 14112 + 3872) * 2;

    int C = 128;
    const int cands[5] = {2048, 1024, 512, 256, 128};
    for (int i = 0; i < 5; ++i) {
        if (FIXED_B + (size_t)cands[i] * PERT_B <= ws_size) { C = cands[i]; break; }
    }

    unsigned short* c0buf = bufs;
    unsigned short* c1buf = c0buf + (size_t)C * 56448;
    unsigned short* c2buf = c1buf + (size_t)C * 14112;

    convert_lwT<<<dim3(36, 32), 256, 0, stream>>>(lw, lwhT);

    for (int t0 = 0; t0 < 2048; t0 += C) {
        const float* xin = x + (size_t)t0 * 84 * 84 * 4;
        conv0_kernel<<<dim3(42, C), 256, 0, stream>>>(xin, w0, b0, c0buf);
        convh_kernel<42, 21, 0, false><<<dim3(21, C), 256, 0, stream>>>(c0buf, w1, b1, c1buf);
        convh_kernel<21, 11, 1, false><<<dim3(11, C), 256, 0, stream>>>(c1buf, w2, b2, c2buf);
        convh_kernel<11, 6, 1, false><<<dim3(6, C), 256, 0, stream>>>(
            c2buf, w3, b3, feats16 + (size_t)t0 * 1152);
    }

    gemm_mfma<<<dim3(16, 32), 256, 0, stream>>>(feats16, lwhT, lb, xpart);
    lstm10_kernel<<<1, 512, 0, stream>>>(lw, xpart, cin, hin, hs_out);
    logits_kernel<<<144, 256, 0, stream>>>(hs_out, fcw, fcb, outp);
}

// Round 17
// 4260.759 us; speedup vs baseline: 1.0987x; 1.0987x over previous
//
#include <hip/hip_runtime.h>
#include <hip/hip_bf16.h>

// ---------------- helpers ----------------
__device__ inline float fsig(float x) { return 1.0f / (1.0f + __expf(-x)); }
__device__ inline float ftanh(float x) {
    float ax = fabsf(x);
    float e = __expf(-2.0f * ax);
    float r = (1.0f - e) / (1.0f + e);
    return x >= 0.0f ? r : -r;
}
__device__ inline float felu(float x) { return x > 0.0f ? x : expm1f(x); }

typedef _Float16 h2_t __attribute__((ext_vector_type(2)));

__device__ inline unsigned int packh2(float a, float b) {
    unsigned short ua = __builtin_bit_cast(unsigned short, (_Float16)a);
    unsigned short ub = __builtin_bit_cast(unsigned short, (_Float16)b);
    return (unsigned int)ua | ((unsigned int)ub << 16);
}
__device__ inline unsigned short f16bits(float a) {
    return __builtin_bit_cast(unsigned short, (_Float16)a);
}

__device__ inline float dot2acc(unsigned int w, unsigned int h, float acc) {
#if __has_builtin(__builtin_amdgcn_fdot2)
    return __builtin_amdgcn_fdot2(__builtin_bit_cast(h2_t, w), __builtin_bit_cast(h2_t, h), acc, false);
#else
    _Float16 wlo = __builtin_bit_cast(_Float16, (unsigned short)(w & 0xffff));
    _Float16 whi = __builtin_bit_cast(_Float16, (unsigned short)(w >> 16));
    _Float16 hlo = __builtin_bit_cast(_Float16, (unsigned short)(h & 0xffff));
    _Float16 hhi = __builtin_bit_cast(_Float16, (unsigned short)(h >> 16));
    return acc + (float)wlo * (float)hlo + (float)whi * (float)hhi;
#endif
}

// ---------------- conv0: f32 in (CIN=4), f16 out ----------------
__global__ __launch_bounds__(256) void conv0_kernel(const float* __restrict__ in,
                                                    const float* __restrict__ wg,
                                                    const float* __restrict__ bias,
                                                    unsigned short* __restrict__ out) {
    constexpr int W = 84, OW = 42, PAD = 0, WP = W + 2;
    __shared__ float in_s[3 * WP * 4];
    constexpr int NQ = 3 * WP;
    const int tid = threadIdx.x;
    const int oy = blockIdx.x;
    const int t = blockIdx.y;
    const int co = tid & 31;

    for (int q = tid; q < NQ; q += 256) {
        int ky = q / WP;
        int col = q - ky * WP;
        int iy = 2 * oy - PAD + ky;
        int ix = col - 1;
        float4 v = make_float4(0.f, 0.f, 0.f, 0.f);
        if (iy >= 0 && iy < W && ix >= 0 && ix < W)
            v = *(const float4*)&in[(((size_t)t * W + iy) * W + ix) * 4];
        *(float4*)&in_s[q * 4] = v;
    }

    float wr[9][4];
#pragma unroll
    for (int tap = 0; tap < 9; ++tap)
#pragma unroll
        for (int j = 0; j < 4; ++j) wr[tap][j] = wg[(tap * 4 + j) * 32 + co];
    __syncthreads();

    const int g = tid >> 5;
    constexpr int NOX = (OW + 7) / 8;
    float acc[NOX];
#pragma unroll
    for (int m = 0; m < NOX; ++m) acc[m] = 0.f;
#pragma unroll
    for (int ky = 0; ky < 3; ++ky)
#pragma unroll
        for (int kx = 0; kx < 3; ++kx) {
            float w0 = wr[ky * 3 + kx][0], w1 = wr[ky * 3 + kx][1];
            float w2 = wr[ky * 3 + kx][2], w3 = wr[ky * 3 + kx][3];
#pragma unroll
            for (int m = 0; m < NOX; ++m) {
                int ox = g + 8 * m;
                if (ox < OW) {
                    int cs = 2 * ox + kx - PAD + 1;
                    float4 xi = *(const float4*)&in_s[(ky * WP + cs) * 4];
                    acc[m] += xi.x * w0 + xi.y * w1 + xi.z * w2 + xi.w * w3;
                }
            }
        }
    float b = bias[co];
#pragma unroll
    for (int m = 0; m < NOX; ++m) {
        int ox = g + 8 * m;
        if (ox < OW)
            out[(((size_t)t * OW + oy) * OW + ox) * 32 + co] = f16bits(felu(acc[m] + b));
    }
}

// ---------------- convh: f16 in (CIN=32, dot2), f16 or f32 out ----------------
template <int W, int OW, int PAD, bool F32OUT>
__global__ __launch_bounds__(256) void convh_kernel(const unsigned short* __restrict__ in,
                                                    const float* __restrict__ wg,
                                                    const float* __restrict__ bias,
                                                    void* __restrict__ outv) {
    constexpr int WP = W + 2;
    constexpr int OWH = (OW + 1) / 2;
    __shared__ __align__(16) unsigned short in_s[3][WP][32];
    __shared__ float zs[4][OW * 32];

    const int tid = threadIdx.x;
    const int oy = blockIdx.x;
    const int t = blockIdx.y;
    const int co = tid & 31;
    const int cig = (tid >> 5) & 3;
    const int oxh = tid >> 7;

    constexpr int NQ4 = 3 * WP * 4;
    uint4* in_s4 = reinterpret_cast<uint4*>(&in_s[0][0][0]);
    for (int q = tid; q < NQ4; q += 256) {
        int ky = q / (WP * 4);
        int rem = q - ky * (WP * 4);
        int col = rem >> 2, c4 = rem & 3;
        int iy = 2 * oy - PAD + ky;
        int ix = col - 1;
        uint4 v = make_uint4(0u, 0u, 0u, 0u);
        if (iy >= 0 && iy < W && ix >= 0 && ix < W)
            v = *(const uint4*)&in[(((size_t)t * W + iy) * W + ix) * 32 + c4 * 8];
        in_s4[q] = v;
    }

    unsigned int wr[9][4];
#pragma unroll
    for (int tap = 0; tap < 9; ++tap)
#pragma unroll
        for (int p = 0; p < 4; ++p)
            wr[tap][p] = packh2(wg[(tap * 32 + cig * 8 + 2 * p) * 32 + co],
                                wg[(tap * 32 + cig * 8 + 2 * p + 1) * 32 + co]);
    __syncthreads();

    float acc[OWH];
#pragma unroll
    for (int m = 0; m < OWH; ++m) acc[m] = 0.f;
#pragma unroll
    for (int ky = 0; ky < 3; ++ky)
#pragma unroll
        for (int kx = 0; kx < 3; ++kx) {
            unsigned int w0 = wr[ky * 3 + kx][0], w1 = wr[ky * 3 + kx][1];
            unsigned int w2 = wr[ky * 3 + kx][2], w3 = wr[ky * 3 + kx][3];
#pragma unroll
            for (int m = 0; m < OWH; ++m) {
                int ox = oxh * OWH + m;
                if (ox < OW) {
                    int cs = 2 * ox + kx - PAD + 1;
                    uint4 h8 = *(const uint4*)&in_s[ky][cs][cig * 8];
                    acc[m] = dot2acc(w0, h8.x, acc[m]);
                    acc[m] = dot2acc(w1, h8.y, acc[m]);
                    acc[m] = dot2acc(w2, h8.z, acc[m]);
                    acc[m] = dot2acc(w3, h8.w, acc[m]);
                }
            }
        }
#pragma unroll
    for (int m = 0; m < OWH; ++m) {
        int ox = oxh * OWH + m;
        if (ox < OW) zs[cig][ox * 32 + co] = acc[m];
    }
    __syncthreads();

    for (int idx = tid; idx < OW * 32; idx += 256) {
        float s = zs[0][idx] + zs[1][idx] + zs[2][idx] + zs[3][idx] + bias[idx & 31];
        s = felu(s);
        if constexpr (F32OUT)
            ((float*)outv)[(((size_t)t * OW + oy) * OW) * 32 + idx] = s;
        else
            ((unsigned short*)outv)[(((size_t)t * OW + oy) * OW) * 32 + idx] = f16bits(s);
    }
}

// ---------------- xpart GEMM ----------------
__global__ void gemm_kernel(const float* __restrict__ A, const float* __restrict__ Wx,
                            const float* __restrict__ bias, float* __restrict__ C) {
    __shared__ float As[32][64];
    __shared__ float Bs[32][64];
    const int bn = blockIdx.x, bm = blockIdx.y;
    const int tx = threadIdx.x, ty = threadIdx.y;
    const int tid = ty * 16 + tx;
    float acc[4][4] = {};
    for (int k0 = 0; k0 < 1152; k0 += 32) {
        {
            int r = tid >> 3;
            int c = (tid & 7) * 4;
            float4 a0 = *(const float4*)&A[(size_t)(bm * 64 + r) * 1152 + k0 + c];
            float4 a1 = *(const float4*)&A[(size_t)(bm * 64 + r + 32) * 1152 + k0 + c];
            As[c + 0][r] = a0.x; As[c + 1][r] = a0.y; As[c + 2][r] = a0.z; As[c + 3][r] = a0.w;
            As[c + 0][r + 32] = a1.x; As[c + 1][r + 32] = a1.y; As[c + 2][r + 32] = a1.z; As[c + 3][r + 32] = a1.w;
            int rb = tid >> 4;
            int cb = (tid & 15) * 4;
            *(float4*)&Bs[rb][cb] = *(const float4*)&Wx[(size_t)(k0 + rb) * 1024 + bn * 64 + cb];
            *(float4*)&Bs[rb + 16][cb] = *(const float4*)&Wx[(size_t)(k0 + rb + 16) * 1024 + bn * 64 + cb];
        }
        __syncthreads();
#pragma unroll
        for (int kk = 0; kk < 32; ++kk) {
            float4 a = *(float4*)&As[kk][ty * 4];
            float4 b = *(float4*)&Bs[kk][tx * 4];
            acc[0][0] += a.x * b.x; acc[0][1] += a.x * b.y; acc[0][2] += a.x * b.z; acc[0][3] += a.x * b.w;
            acc[1][0] += a.y * b.x; acc[1][1] += a.y * b.y; acc[1][2] += a.y * b.z; acc[1][3] += a.y * b.w;
            acc[2][0] += a.z * b.x; acc[2][1] += a.z * b.y; acc[2][2] += a.z * b.z; acc[2][3] += a.z * b.w;
            acc[3][0] += a.w * b.x; acc[3][1] += a.w * b.y; acc[3][2] += a.w * b.z; acc[3][3] += a.w * b.w;
        }
        __syncthreads();
    }
#pragma unroll
    for (int i = 0; i < 4; ++i) {
        int row = bm * 64 + ty * 4 + i;
#pragma unroll
        for (int j = 0; j < 4; ++j) {
            int col = bn * 64 + tx * 4 + j;
            C[(size_t)row * 1024 + col] = acc[i][j] + bias[col];
        }
    }
}

// ---------------- LSTM lstm7: 8 waves, k-split-2, gate-major (best measured: 3277us) ----
__global__ __attribute__((amdgpu_flat_work_group_size(512, 512), amdgpu_num_vgpr(256)))
void lstm7_kernel(const float* __restrict__ lstm_w,
                  const float* __restrict__ xpart,
                  const float* __restrict__ c_in,
                  const float* __restrict__ h_in,
                  float* __restrict__ hs_out) {
    __shared__ __align__(16) unsigned int wl[512][52];      // 48 used per row
    __shared__ float zsm[2][4][256];
    __shared__ __align__(16) unsigned int hpk[2][2][68];    // [buf][slice][64 pairs + pad]

    const int tid = threadIdx.x;
    const int s = tid >> 8;        // k-half
    const int u = tid & 255;       // unit

    for (int q = 0; q < 4; ++q)
        for (int p = 0; p < 12; ++p) {
            int gp = 64 * s + p;
            wl[tid][q * 12 + p] = packh2(lstm_w[(size_t)(1152 + 2 * gp) * 1024 + 256 * q + u],
                                         lstm_w[(size_t)(1152 + 2 * gp + 1) * 1024 + 256 * q + u]);
        }
    unsigned int wreg[4][52];
#pragma unroll
    for (int q = 0; q < 4; ++q)
        for (int p = 12; p < 64; ++p) {
            int gp = 64 * s + p;
            wreg[q][p - 12] = packh2(lstm_w[(size_t)(1152 + 2 * gp) * 1024 + 256 * q + u],
                                     lstm_w[(size_t)(1152 + 2 * gp + 1) * 1024 + 256 * q + u]);
        }

    float c_state = c_in[u];       // x2 redundant (s=0 and s=1 threads)
    if (tid < 256) {
        unsigned short* hrow = (unsigned short*)&hpk[0][u >> 7][0];
        hrow[u & 127] = f16bits(h_in[u]);
    }
    __syncthreads();

    float xp0 = xpart[u], xp1 = xpart[256 + u], xp2 = xpart[512 + u], xp3 = xpart[768 + u];

    for (int t = 0; t < 2048; ++t) {
        const int cur = t & 1;
        const uint4* hq = reinterpret_cast<const uint4*>(&hpk[cur][s][0]);

        float acc[4] = {0.f, 0.f, 0.f, 0.f};
        {   // LDS-weight chunks: pairs 0..11 (h chunks 0..2)
            uint4 hA = hq[0], hB = hq[1], hC = hq[2];
#pragma unroll
            for (int q = 0; q < 4; ++q) {
                uint4 wa = *(const uint4*)&wl[tid][q * 12];
                uint4 wb = *(const uint4*)&wl[tid][q * 12 + 4];
                uint4 wc = *(const uint4*)&wl[tid][q * 12 + 8];
                acc[q] = dot2acc(wa.x, hA.x, acc[q]); acc[q] = dot2acc(wa.y, hA.y, acc[q]);
                acc[q] = dot2acc(wa.z, hA.z, acc[q]); acc[q] = dot2acc(wa.w, hA.w, acc[q]);
                acc[q] = dot2acc(wb.x, hB.x, acc[q]); acc[q] = dot2acc(wb.y, hB.y, acc[q]);
                acc[q] = dot2acc(wb.z, hB.z, acc[q]); acc[q] = dot2acc(wb.w, hB.w, acc[q]);
                acc[q] = dot2acc(wc.x, hC.x, acc[q]); acc[q] = dot2acc(wc.y, hC.y, acc[q]);
                acc[q] = dot2acc(wc.z, hC.z, acc[q]); acc[q] = dot2acc(wc.w, hC.w, acc[q]);
            }
        }
#pragma unroll
        for (int c = 3; c < 16; ++c) {   // register chunks: pairs 12..63
            uint4 h4 = hq[c];
            const int r = 4 * (c - 3);
#pragma unroll
            for (int q = 0; q < 4; ++q) {
                acc[q] = dot2acc(wreg[q][r + 0], h4.x, acc[q]);
                acc[q] = dot2acc(wreg[q][r + 1], h4.y, acc[q]);
                acc[q] = dot2acc(wreg[q][r + 2], h4.z, acc[q]);
                acc[q] = dot2acc(wreg[q][r + 3], h4.w, acc[q]);
            }
        }
        zsm[s][0][u] = acc[0];
        zsm[s][1][u] = acc[1];
        zsm[s][2][u] = acc[2];
        zsm[s][3][u] = acc[3];

        float xn0 = 0.f, xn1 = 0.f, xn2 = 0.f, xn3 = 0.f;
        if (t + 1 < 2048) {
            const float* xr = &xpart[(size_t)(t + 1) * 1024];
            xn0 = xr[u]; xn1 = xr[256 + u]; xn2 = xr[512 + u]; xn3 = xr[768 + u];
        }

        asm volatile("s_waitcnt lgkmcnt(0)\n\ts_barrier" ::: "memory");

        // gates (all 512 threads, x2 redundant)
        float zi = zsm[0][0][u] + zsm[1][0][u] + xp0;
        float zj = zsm[0][1][u] + zsm[1][1][u] + xp1;
        float zf = zsm[0][2][u] + zsm[1][2][u] + xp2;
        float zo = zsm[0][3][u] + zsm[1][3][u] + xp3;
        c_state = c_state * fsig(zf + 1.0f) + fsig(zi) * ftanh(zj);
        float h = ftanh(c_state) * fsig(zo);
        if (tid < 256) {
            hs_out[(size_t)t * 256 + u] = h;
            unsigned short* hrow = (unsigned short*)&hpk[cur ^ 1][u >> 7][0];
            hrow[u & 127] = f16bits(h);
        }

        asm volatile("s_waitcnt lgkmcnt(0)\n\ts_barrier" ::: "memory");
        xp0 = xn0; xp1 = xn1; xp2 = xn2; xp3 = xn3;
    }
}

// ---------------- logits ----------------
__global__ void logits_kernel(const float* __restrict__ hs, const float* __restrict__ fc_w,
                              const float* __restrict__ fc_b, float* __restrict__ out) {
    int idx = blockIdx.x * 256 + threadIdx.x;
    if (idx >= 2048 * 18) return;
    int t = idx / 18, n = idx % 18;
    float acc = fc_b[n];
    const float* hrow = hs + (size_t)t * 256;
#pragma unroll 4
    for (int k = 0; k < 256; ++k) acc += hrow[k] * fc_w[k * 18 + n];
    out[idx] = acc;
}

// ---------------- launch ----------------
extern "C" void kernel_launch(void* const* d_in, const int* in_sizes, int n_in,
                              void* d_out, int out_size, void* d_ws, size_t ws_size,
                              hipStream_t stream) {
    const float* x   = (const float*)d_in[0];
    const float* w0  = (const float*)d_in[1];
    const float* b0  = (const float*)d_in[2];
    const float* w1  = (const float*)d_in[3];
    const float* b1  = (const float*)d_in[4];
    const float* w2  = (const float*)d_in[5];
    const float* b2  = (const float*)d_in[6];
    const float* w3  = (const float*)d_in[7];
    const float* b3  = (const float*)d_in[8];
    const float* lw  = (const float*)d_in[9];
    const float* lb  = (const float*)d_in[10];
    const float* fcw = (const float*)d_in[11];
    const float* fcb = (const float*)d_in[12];
    const float* cin = (const float*)d_in[13];
    const float* hin = (const float*)d_in[14];

    float* outp = (float*)d_out;
    float* hs_out = outp + 2048 * 18;

    const size_t FIXED_B = ((size_t)2048 * 1152 + (size_t)2048 * 1024) * 4;
    const size_t PERT_B = ((size_t)56448 + 14112 + 3872) * 2;

    int C = 128;
    const int cands[5] = {2048, 1024, 512, 256, 128};
    for (int i = 0; i < 5; ++i) {
        if (FIXED_B + (size_t)cands[i] * PERT_B <= ws_size) { C = cands[i]; break; }
    }

    float* feats = (float*)d_ws;
    float* xpart = feats + (size_t)2048 * 1152;
    unsigned short* c0buf = (unsigned short*)(xpart + (size_t)2048 * 1024);
    unsigned short* c1buf = c0buf + (size_t)C * 56448;
    unsigned short* c2buf = c1buf + (size_t)C * 14112;

    for (int t0 = 0; t0 < 2048; t0 += C) {
        const float* xin = x + (size_t)t0 * 84 * 84 * 4;
        conv0_kernel<<<dim3(42, C), 256, 0, stream>>>(xin, w0, b0, c0buf);
        convh_kernel<42, 21, 0, false><<<dim3(21, C), 256, 0, stream>>>(c0buf, w1, b1, c1buf);
        convh_kernel<21, 11, 1, false><<<dim3(11, C), 256, 0, stream>>>(c1buf, w2, b2, c2buf);
        convh_kernel<11, 6, 1, true><<<dim3(6, C), 256, 0, stream>>>(c2buf, w3, b3,
                                                                     feats + (size_t)t0 * 1152);
    }

    gemm_kernel<<<dim3(16, 32), dim3(16, 16), 0, stream>>>(feats, lw, lb, xpart);
    lstm7_kernel<<<1, 512, 0, stream>>>(lw, xpart, cin, hin, hs_out);
    logits_kernel<<<144, 256, 0, stream>>>(hs_out, fcw, fcb, outp);
}